// Round 8
// baseline (188.970 us; speedup 1.0000x reference)
//
#include <hip/hip_runtime.h>

// ContourIntegrationLayer: depthwise 3x3 conv, center tap masked to 0,
// SAME padding, + residual. x: [B,H,W,C] fp32 NHWC, kernel: [3,3,C] fp32.
// B=32 H=56 W=56 C=256.
//
// R1: XCD swizzle (kept). R2: P=14 strip (kept).
// R3/R5: reg-resident taps / reg double-buffer -> allocator spills. Dead end.
// R4: taps-in-LDS load-consume: clean but latency-bound (81.7us).
// R6: per-wave async DMA pipeline, depth 2 rows: 67.5us, 4 blocks/CU.
//     Residual 200-600cy DMA latency exposed per step.
// R7: depth 4 rows but LDS arithmetic error: 58KB/block -> 2 blocks/CU,
//     occupancy 34->19%, 72.6us. Pipeline correct, budget blown.
// R8: cooperative block staging. The 4 waves of a block are at w0..w0+3 of
//     the same (b,hc) (56%4==0 -> never wraps); per 2-row slot the block
//     needs only 6 unique columns (w0-1..w0+4), not 4x3. LDS: 2 slots x 2
//     rows x 6 cols + taps = 33792 B -> 4 blocks/CU restored AND depth-4
//     kept AND per-wave DMA ops halved (3/step). Cross-wave handoff via
//     counted-vmcnt-before-raw-barrier (bar1) and lgkm0+barrier after reads
//     (bar2) -- the 8-phase pattern; no __syncthreads in the loop.

#define BB 32
#define HH 56
#define WW 56
#define C4 64            // 256 channels / 4 per float4
#define NXCD 8
#define P 14             // output rows per thread (56 = 4*14)
#define NHC 4            // h-chunks
#define ROWSTR (WW * C4) // float4 stride between image rows = 3584

typedef float f32x4 __attribute__((ext_vector_type(4)));

__device__ __forceinline__ void ntstore4(const float4& v, float4* p) {
    __builtin_nontemporal_store(*(const f32x4*)&v, (f32x4*)p);
}

__device__ __forceinline__ void async16(const float4* g, float4* l) {
    // 16B/lane, global (per-lane addr) -> LDS (wave-uniform base + lane*16)
    __builtin_amdgcn_global_load_lds(
        (const __attribute__((address_space(1))) void*)g,
        (__attribute__((address_space(3))) void*)l,
        16, 0, 0);
}

#define WAITV2 asm volatile("s_waitcnt vmcnt(2)" ::: "memory")
#define WAITV3 asm volatile("s_waitcnt vmcnt(3)" ::: "memory")
#define WAITV5 asm volatile("s_waitcnt vmcnt(5)" ::: "memory")
#define LGKM0  asm volatile("s_waitcnt lgkmcnt(0)" ::: "memory")
#define BAR    __builtin_amdgcn_s_barrier()

// CT: d = k0*L + k1*C + k2*R          (T(y) -> feeds out(y+1))
#define CT(d, L, C, R)                                      \
    {                                                       \
        float4 K0 = kl[0*C4], K1 = kl[1*C4], K2 = kl[2*C4]; \
        (d).x = K0.x*(L).x + K1.x*(C).x + K2.x*(R).x;       \
        (d).y = K0.y*(L).y + K1.y*(C).y + K2.y*(R).y;       \
        (d).z = K0.z*(L).z + K1.z*(C).z + K2.z*(R).z;       \
        (d).w = K0.w*(L).w + K1.w*(C).w + K2.w*(R).w;       \
    }
// AM: d += C + k3*L + k5*R            (M(y)+residual -> out(y))
#define AM(d, L, C, R)                                      \
    {                                                       \
        float4 K3 = kl[3*C4], K5 = kl[5*C4];                \
        (d).x += (C).x + K3.x*(L).x + K5.x*(R).x;           \
        (d).y += (C).y + K3.y*(L).y + K5.y*(R).y;           \
        (d).z += (C).z + K3.z*(L).z + K5.z*(R).z;           \
        (d).w += (C).w + K3.w*(L).w + K5.w*(R).w;           \
    }
// AB: d += k6*L + k7*C + k8*R         (B(y) -> completes out(y-1))
#define AB(d, L, C, R)                                      \
    {                                                       \
        float4 K6 = kl[6*C4], K7 = kl[7*C4], K8 = kl[8*C4]; \
        (d).x += K6.x*(L).x + K7.x*(C).x + K8.x*(R).x;      \
        (d).y += K6.y*(L).y + K7.y*(C).y + K8.y*(R).y;      \
        (d).z += K6.z*(L).z + K7.z*(C).z + K8.z*(R).z;      \
        (d).w += K6.w*(L).w + K7.w*(C).w + K8.w*(R).w;      \
    }

// read both rows of a slot: wave wv uses cols wv,wv+1,wv+2 of the 6.
// layout: lds_rows[slot][row][col][lane]; flat = slot*768 + row*384 + col*64
#define READ2C(slot)                                        \
    {                                                       \
        const float4* q = lrb + (slot)*768 + wv*64 + lane;  \
        float4 a = q[0],   bq = q[64],  cq = q[128];        \
        float4 d = q[384], e  = q[448], f  = q[512];        \
        L0 = wl ? a : zero;  C0 = bq;  R0 = wr ? cq : zero; \
        L1 = wl ? d : zero;  C1 = e;   R1 = wr ? f  : zero; \
    }

// cooperative stage of rows (ra, rb) into a slot: 12 (row,col) pairs,
// wave wv issues pairs 3*wv .. 3*wv+2 (precomputed rs*/gc*/lo*).
#define STAGE2C(ra, rb, slot)                               \
    {                                                       \
        int ya = (ra); ya = ya < 0 ? 0 : (ya > HH-1 ? HH-1 : ya); \
        int yb = (rb); yb = yb < 0 ? 0 : (yb > HH-1 ? HH-1 : yb); \
        int y0 = rs0 ? yb : ya;                             \
        int y1 = rs1 ? yb : ya;                             \
        int y2 = rs2 ? yb : ya;                             \
        float4* lb = lrb + (slot)*768;                      \
        async16(xim + (size_t)y0*ROWSTR + gc0, lb + lo0);   \
        async16(xim + (size_t)y1*ROWSTR + gc1, lb + lo1);   \
        async16(xim + (size_t)y2*ROWSTR + gc2, lb + lo2);   \
    }

// full interior row: completes out(y-1), stores, advances partials
#define ROWFULL(L, C, R)                                    \
    {                                                       \
        AB(pA, L, C, R);                                    \
        ntstore4(pA, op); op += ROWSTR;                     \
        AM(pB, L, C, R);                                    \
        pA = pB;                                            \
        CT(pB, L, C, R);                                    \
    }

__global__ __launch_bounds__(256, 4) void contour_kernel(
    const float4* __restrict__ x,     // [B*H*W*C4]
    const float4* __restrict__ kern,  // [9*C4]
    float4* __restrict__ out)         // [B*H*W*C4]
{
    // taps staged once (the __syncthreads here is BEFORE any DMA)
    __shared__ float4 lds_k[9 * C4];           //  9216 B
    __shared__ float4 lds_rows[2][2][6][C4];   // 24576 B, block-shared
    for (int i = threadIdx.x; i < 9 * C4; i += 256)
        lds_k[i] = kern[i];
    __syncthreads();

    // XCD swizzle: each XCD owns a contiguous chunk (4 whole images).
    const int nblocks = gridDim.x;          // 1792, divisible by 8
    const int per_xcd = nblocks / NXCD;     // 224
    const int blk = (blockIdx.x % NXCD) * per_xcd + blockIdx.x / NXCD;

    const int lane = threadIdx.x & 63;      // == c4
    const int wv   = threadIdx.x >> 6;
    const int sblk = blk * 4;               // strip index of wave 0
    const int w0   = sblk % WW;             // multiple of 4 -> never wraps
    const int tt   = sblk / WW;
    const int hc   = tt & (NHC - 1);        // block-uniform
    const int b    = tt >> 2;               // block-uniform
    const int w    = w0 + wv;               // wave-uniform

    const float4 zero = make_float4(0.f, 0.f, 0.f, 0.f);
    const float4* kl  = lds_k + lane;       // tap i at kl[i*C4]
    float4*       lrb = &lds_rows[0][0][0][0];  // slot stride 768

    const bool wl = (w > 0);
    const bool wr = (w < WW - 1);

    // staging assignment: pair p = 3*wv + i; row = p/6, col = p%6;
    // global col = clamp(w0-1+col); lds offset = row*384 + col*64.
    int rs0, rs1, rs2, gc0, gc1, gc2, lo0, lo1, lo2;
    {
        int p, c, wc;
        p = wv*3 + 0; rs0 = (p >= 6); c = p - 6*rs0;
        wc = w0 - 1 + c; wc = wc < 0 ? 0 : (wc > WW-1 ? WW-1 : wc);
        gc0 = wc * C4 + lane; lo0 = rs0*384 + c*64;
        p = wv*3 + 1; rs1 = (p >= 6); c = p - 6*rs1;
        wc = w0 - 1 + c; wc = wc < 0 ? 0 : (wc > WW-1 ? WW-1 : wc);
        gc1 = wc * C4 + lane; lo1 = rs1*384 + c*64;
        p = wv*3 + 2; rs2 = (p >= 6); c = p - 6*rs2;
        wc = w0 - 1 + c; wc = wc < 0 ? 0 : (wc > WW-1 ? WW-1 : wc);
        gc2 = wc * C4 + lane; lo2 = rs2*384 + c*64;
    }

    const int h0 = hc * P;
    const float4* xim = x + (size_t)(b * HH) * ROWSTR;
    float4* op = out + (size_t)(b * HH + h0) * ROWSTR + w * C4 + lane;

    float4 L0, C0, R0, L1, C1, R1;   // current row pair (short-lived)
    float4 pA, pB;                   // pending partials

    // prologue: slot0 <- rows (h0-1, h0); slot1 <- rows (h0+1, h0+2)
    STAGE2C(h0 - 1, h0,     0);
    STAGE2C(h0 + 1, h0 + 2, 1);

    // step0: consume slot0 = rows h0-1 (halo: T only), h0 (M,T). No stage.
    WAITV3;                          // allow slot1's 3 -> slot0 retired
    BAR;                             // all waves' slot0 stages retired
    READ2C(0);
    LGKM0;
    BAR;                             // all waves done reading slot0
    if (h0 > 0) { CT(pB, L0, C0, R0); } else { pB = zero; }
    AM(pB, L1, C1, R1);              // pB = out(h0) partial
    pA = pB;
    CT(pB, L1, C1, R1);              // pB = T(h0)

    // step1: consume slot1 = rows h0+1,h0+2 ; stage slot0 <- h0+3,h0+4
    STAGE2C(h0 + 3, h0 + 4, 0);
    WAITV3;                          // allow new 3 -> slot1 retired
    BAR;
    READ2C(1);
    LGKM0;
    BAR;
    ROWFULL(L0, C0, R0);             // stores out(h0)
    ROWFULL(L1, C1, R1);             // stores out(h0+1)

    // steps2..5: rows h0+3..h0+10 (steady, vmcnt(5) = 3 stages + 2 stores)
    int sr = h0 + 5;
    #pragma unroll 1
    for (int j = 0; j < 2; ++j) {
        STAGE2C(sr, sr + 1, 1); sr += 2;
        WAITV5; BAR; READ2C(0); LGKM0; BAR;
        ROWFULL(L0, C0, R0);
        ROWFULL(L1, C1, R1);
        STAGE2C(sr, sr + 1, 0); sr += 2;
        WAITV5; BAR; READ2C(1); LGKM0; BAR;
        ROWFULL(L0, C0, R0);
        ROWFULL(L1, C1, R1);
    }

    // step6: consume slot0 = rows h0+11,h0+12 ; stage slot1 <- h0+13,h0+14
    STAGE2C(sr, sr + 1, 1);
    WAITV5; BAR; READ2C(0); LGKM0; BAR;
    ROWFULL(L0, C0, R0);             // stores out(h0+10)
    ROWFULL(L1, C1, R1);             // stores out(h0+11)

    // step7: consume slot1 = rows h0+13, h0+14(halo). No stage.
    WAITV2;                          // allow step6's 2 stores -> slot1 retired
    BAR;
    READ2C(1);
    LGKM0;
    AB(pA, L0, C0, R0);              // completes out(h0+12)
    ntstore4(pA, op); op += ROWSTR;
    AM(pB, L0, C0, R0);              // pB = out(h0+13) partial
    pA = pB;
    const bool hasbot = (h0 + P < HH);   // block-uniform
    if (hasbot) { AB(pA, L1, C1, R1); } // B(h0+14)
    ntstore4(pA, op);                // out(h0+13)
}

extern "C" void kernel_launch(void* const* d_in, const int* in_sizes, int n_in,
                              void* d_out, int out_size, void* d_ws, size_t ws_size,
                              hipStream_t stream) {
    const float4* x    = (const float4*)d_in[0];
    const float4* kern = (const float4*)d_in[1];
    float4* out        = (float4*)d_out;

    const int total = BB * NHC * WW * C4;           // 458,752 threads
    const int block = 256;
    const int grid  = (total + block - 1) / block;  // 1792 blocks (8*224)
    contour_kernel<<<grid, block, 0, stream>>>(x, kern, out);
}